// Round 1
// baseline (313.377 us; speedup 1.0000x reference)
//
#include <hip/hip_runtime.h>

// ---- hash / bucket constants ----
#define HBITS 19
#define HSIZE (1u << HBITS)
#define HMASK (HSIZE - 1u)
#define EMPTY_KEY 0xFFFFFFFFu
#define SLOTS 8   // direct slots per voxel; overflow (P~1e-4) goes to chain

__device__ __forceinline__ unsigned hash_key(unsigned k) {
    return (k * 2654435761u) >> (32 - HBITS);
}

__device__ __forceinline__ unsigned pack_key(int4 c) {
    // c.x = batch (<4), c.y/z/w = xyz in [0,256)
    return ((unsigned)c.x << 24) | ((unsigned)c.y << 16) |
           ((unsigned)c.z << 8) | (unsigned)c.w;
}

// Kernel A: insert voxel keys; htab[h] = (key, min original index).
__global__ __launch_bounds__(256)
void build_hash(const int4* __restrict__ tgt_coords, int M,
                uint2* __restrict__ htab) {
    int v = blockIdx.x * blockDim.x + threadIdx.x;
    if (v >= M) return;
    unsigned key = pack_key(tgt_coords[v]);
    unsigned h = hash_key(key);
    while (true) {
        unsigned prev = atomicCAS(&htab[h].x, EMPTY_KEY, key);
        if (prev == EMPTY_KEY || prev == key) {
            atomicMin(&htab[h].y, (unsigned)v);   // canonical = min index
            break;
        }
        h = (h + 1u) & HMASK;
    }
}

// Kernel B: each point probes the hash for its canonical voxel and claims a
// bucket slot. cnt[] init = -1 (0xFF memset) so atomicAdd+1 gives slot 0,1,...
__global__ __launch_bounds__(256)
void fill_slots(const int* __restrict__ pts_idx,
                const int4* __restrict__ tgt_coords,
                const uint2* __restrict__ htab,
                int BN,
                int* __restrict__ cnt,      // (M) init -1
                int* __restrict__ slotbuf,  // (M*SLOTS) no init needed
                int* __restrict__ ohead,    // (M) init -1
                int* __restrict__ nxt) {    // (BN) no init needed
    int p = blockIdx.x * blockDim.x + threadIdx.x;
    if (p >= BN) return;
    int vox = pts_idx[p];
    unsigned key = pack_key(tgt_coords[vox]);
    unsigned h = hash_key(key);
    uint2 e = htab[h];
    while (e.x != key) { h = (h + 1u) & HMASK; e = htab[h]; }
    int c = (int)e.y;
    int idx = atomicAdd(&cnt[c], 1) + 1;
    if (idx < SLOTS) slotbuf[c * SLOTS + idx] = p;
    else             nxt[p] = atomicExch(&ohead[c], p);   // rare
}

// Kernel E: FUSED gather-mean + 96->32 GEMV.
//  - group of 32 lanes per voxel (VPB=8 voxels / 256-thread block)
//  - phase 1 (gather): lane g sums img channels 2g,2g+1 over the voxel's
//    points (coalesced 256B row reads, all slot loads independent), writes
//    the 96-wide fused x-vector [tgt(32) | mean(64)] into LDS — mean NEVER
//    touches HBM (saves 102.4 MB round trip vs split kernels).
//  - phase 2 (GEMV): lane g computes out channel g: W column g lives in 96
//    VGPRs (coalesced 128B/row loads, L1-hot after first block); x is read
//    back as uniform-per-group ds_read_b128 broadcasts (conflict-free).
//    FMA order per output = bias + k ascending == old matmul_scalar exactly.
#define VPB 8
__global__ __launch_bounds__(256)
void gather_fuse(const float2* __restrict__ pf2,   // (BN,64) as (BN,32) float2
                 const float* __restrict__ tgtf,   // (M,32)
                 const int* __restrict__ cnt,
                 const int4* __restrict__ slot4,   // slotbuf as (M,2) int4
                 const int* __restrict__ ohead,
                 const int* __restrict__ nxt,
                 const float* __restrict__ W,      // (96,32)
                 const float* __restrict__ bias,   // (32,)
                 int M,
                 float* __restrict__ out) {        // (M,32)
    // row stride 104 floats: 416 B = 16B-aligned (b128-safe), %32 banks = 8
    __shared__ __align__(16) float xs[VPB][104];

    int t = threadIdx.x;
    int grp = t >> 5;
    int g   = t & 31;
    int v = blockIdx.x * VPB + grp;
    bool valid = (v < M);

    if (valid) {
        // ---- phase 1: gather-mean into LDS ----
        int n = cnt[v] + 1;
        int4 sa = make_int4(0, 0, 0, 0), sb = make_int4(0, 0, 0, 0);
        if (n > 0) sa = slot4[(size_t)v * 2];
        if (n > 4) sb = slot4[(size_t)v * 2 + 1];
        float2 f0 = {0,0}, f1 = {0,0}, f2 = {0,0}, f3 = {0,0};
        float2 f4 = {0,0}, f5 = {0,0}, f6 = {0,0}, f7 = {0,0};
        if (n > 0) f0 = pf2[(size_t)sa.x * 32 + g];
        if (n > 1) f1 = pf2[(size_t)sa.y * 32 + g];
        if (n > 2) f2 = pf2[(size_t)sa.z * 32 + g];
        if (n > 3) f3 = pf2[(size_t)sa.w * 32 + g];
        if (n > 4) f4 = pf2[(size_t)sb.x * 32 + g];
        if (n > 5) f5 = pf2[(size_t)sb.y * 32 + g];
        if (n > 6) f6 = pf2[(size_t)sb.z * 32 + g];
        if (n > 7) f7 = pf2[(size_t)sb.w * 32 + g];
        float sx = ((f0.x + f1.x) + (f2.x + f3.x)) + ((f4.x + f5.x) + (f6.x + f7.x));
        float sy = ((f0.y + f1.y) + (f2.y + f3.y)) + ((f4.y + f5.y) + (f6.y + f7.y));
        if (n > SLOTS) {   // extremely rare overflow chain
            int p = ohead[v];
            while (p >= 0) {
                float2 f = pf2[(size_t)p * 32 + g];
                sx += f.x; sy += f.y;
                p = nxt[p];
            }
        }
        float inv = 1.0f / fmaxf((float)n, 1.0f);
        xs[grp][g] = tgtf[(size_t)v * 32 + g];                       // x[0..31]
        *reinterpret_cast<float2*>(&xs[grp][32 + 2 * g]) =
            make_float2(sx * inv, sy * inv);                         // x[32..95]
    }

    // W column g -> 96 VGPRs (uniform-per-group rows; lanes 0..31 coalesce,
    // lanes 32..63 hit the same 128B line; L1/L2-hot after first blocks)
    float wcol[96];
#pragma unroll
    for (int k = 0; k < 96; ++k) wcol[k] = W[k * 32 + g];

    __syncthreads();

    if (valid) {
        // ---- phase 2: per-lane GEMV for out channel g ----
        float acc = bias[g];
#pragma unroll
        for (int k4 = 0; k4 < 24; ++k4) {
            float4 x = *reinterpret_cast<const float4*>(&xs[grp][k4 * 4]);
            acc = fmaf(x.x, wcol[4 * k4 + 0], acc);
            acc = fmaf(x.y, wcol[4 * k4 + 1], acc);
            acc = fmaf(x.z, wcol[4 * k4 + 2], acc);
            acc = fmaf(x.w, wcol[4 * k4 + 3], acc);
        }
        out[(size_t)v * 32 + g] = acc;   // 128B coalesced per group
    }
}

extern "C" void kernel_launch(void* const* d_in, const int* in_sizes, int n_in,
                              void* d_out, int out_size, void* d_ws, size_t ws_size,
                              hipStream_t stream) {
    const float* pfeat      = (const float*)d_in[0];  // (BN,64)
    const float* tgt_feats  = (const float*)d_in[1];  // (M,32)
    const float* W_fuse     = (const float*)d_in[2];  // (96,32)
    const float* b_fuse     = (const float*)d_in[3];  // (32,)
    const int*   tgt_coords = (const int*)d_in[4];    // (M,4)
    const int*   pts_idx    = (const int*)d_in[5];    // (BN,)
    float* out = (float*)d_out;                       // (M,32)

    const int M  = in_sizes[4] / 4;
    const int BN = in_sizes[5];

    // workspace: [htab 4MB | cnt M | ohead M]  <- single 0xFF memset region
    //            [slotbuf M*8 | nxt BN] <- write-before-read
    char* ws = (char*)d_ws;
    uint2* htab    = (uint2*)ws;
    size_t off = (size_t)HSIZE * 8;
    int*   cnt     = (int*)(ws + off);              off += (size_t)M * 4;
    int*   ohead   = (int*)(ws + off);              off += (size_t)M * 4;
    int*   slotbuf = (int*)(ws + off);              off += (size_t)M * SLOTS * 4;
    int*   nxt     = (int*)(ws + off);

    size_t ff_bytes = (size_t)HSIZE * 8 + (size_t)M * 8;  // htab + cnt + ohead
    hipMemsetAsync(htab, 0xFF, ff_bytes, stream);  // EMPTY_KEY / UINT_MAX / -1 / -1

    const int TB = 256;
    build_hash<<<(M + TB - 1) / TB, TB, 0, stream>>>(
        (const int4*)tgt_coords, M, htab);
    fill_slots<<<(BN + TB - 1) / TB, TB, 0, stream>>>(
        pts_idx, (const int4*)tgt_coords, htab, BN, cnt, slotbuf, ohead, nxt);
    gather_fuse<<<(M + VPB - 1) / VPB, TB, 0, stream>>>(
        (const float2*)pfeat, tgt_feats, cnt, (const int4*)slotbuf, ohead, nxt,
        W_fuse, b_fuse, M, out);
}